// Round 3
// baseline (24833.012 us; speedup 1.0000x reference)
//
#include <hip/hip_runtime.h>
#include <cstdint>

// B=32, S=64, T=64, D=256, H=512, 3H=1536, VOUT=32000
// Round 3: correctness-first ALL-FP32 implementation (no MFMA, no bf16).
// Purpose: establish a passing baseline and isolate the round-2 bug to the
// MFMA path (if this passes) or the dataflow (if this fails).

__device__ __forceinline__ float sigm(float x) { return 1.f / (1.f + __expf(-x)); }

// ---------------- init ----------------
__global__ void k_zero2(float* a, float* b) {
    int i = blockIdx.x * 256 + threadIdx.x;
    a[i] = 0.f; b[i] = 0.f;
}

// ---------------- embedding gathers (fp32 row copies) ----------------
// out row r = s*32+b  <- E_enc[input_seq[b*64+s]]
__global__ void k_gather_enc(const int* __restrict__ seq, const float* __restrict__ E,
                             float* __restrict__ out) {
    int r = blockIdx.x;            // s*32+b
    int s = r >> 5, b = r & 31;
    int tok = seq[b * 64 + s];
    float4 v = ((const float4*)(E + (size_t)tok * 256))[threadIdx.x];
    ((float4*)(out + (size_t)r * 256))[threadIdx.x] = v;
}
// out row r = t*32+b  <- E_dec[t==0 ? 0 : target[b*64 + t-1]]
__global__ void k_gather_dec(const int* __restrict__ tgt, const float* __restrict__ E,
                             float* __restrict__ out) {
    int r = blockIdx.x;            // t*32+b
    int t = r >> 5, b = r & 31;
    int tok = (t == 0) ? 0 : tgt[b * 64 + (t - 1)];
    float4 v = ((const float4*)(E + (size_t)tok * 256))[threadIdx.x];
    ((float4*)(out + (size_t)r * 256))[threadIdx.x] = v;
}

// ---------------- simple tiled fp32 GEMM ----------------
// C[M,N] = A[M,K] @ W[N, coloff:coloff+K]^T + bias
// grid (N/64, M/64), block 256 (tx=tid&15 over N, ty=tid>>4 over M), 4x4 per thread.
// out_mode 0: outF[m*N+n]; 1: outF[(b*64+t)*N+n] with m=t*32+b (logits remap).
__global__ __launch_bounds__(256) void k_sgemm(
    const float* __restrict__ A, int lda,
    const float* __restrict__ W, int ldw, int coloff,
    const float* __restrict__ bias,
    float* __restrict__ outF, int N, int K, int out_mode)
{
    __shared__ float As[16][68];   // [kk][mm], pad 68 keeps float4 reads 16B-aligned
    __shared__ float Ws[16][68];   // [kk][nn]
    int tid = threadIdx.x;
    int tx = tid & 15, ty = tid >> 4;
    int m_base = blockIdx.y * 64;
    int n_base = blockIdx.x * 64;
    float acc[4][4] = {};

    for (int k0 = 0; k0 < K; k0 += 16) {
        #pragma unroll
        for (int i = 0; i < 4; i++) {
            int e = tid + 256 * i;            // 0..1023, bijective
            int mm = e >> 4, kk = e & 15;
            As[kk][mm] = A[(size_t)(m_base + mm) * lda + k0 + kk];
            Ws[kk][mm] = W[(size_t)(n_base + mm) * ldw + coloff + k0 + kk];
        }
        __syncthreads();
        #pragma unroll
        for (int kk = 0; kk < 16; kk++) {
            float4 av = *(const float4*)&As[kk][ty * 4];
            float4 wv = *(const float4*)&Ws[kk][tx * 4];
            float a[4] = {av.x, av.y, av.z, av.w};
            float w[4] = {wv.x, wv.y, wv.z, wv.w};
            #pragma unroll
            for (int i = 0; i < 4; i++)
                #pragma unroll
                for (int j = 0; j < 4; j++)
                    acc[i][j] += a[i] * w[j];
        }
        __syncthreads();
    }

    #pragma unroll
    for (int j = 0; j < 4; j++) {
        int n = n_base + tx * 4 + j;
        float bv = bias ? bias[n] : 0.f;
        #pragma unroll
        for (int i = 0; i < 4; i++) {
            int m = m_base + ty * 4 + i;
            float v = acc[i][j] + bv;
            if (out_mode == 0) {
                outF[(size_t)m * N + n] = v;
            } else {
                int t = m >> 5, b = m & 31;   // m = t*32+b -> out[(b*64+t)*N+n]
                outF[((size_t)(b * 64 + t)) * N + n] = v;
            }
        }
    }
}

#define FDOT4(acc, p, hp) \
    acc += p.x*hp[0] + p.y*hp[1] + p.z*hp[2] + p.w*hp[3];

// ---------------- encoder GRU step ----------------
// grid (2, 32), block 256. thread: (b=blockIdx.y, i=blockIdx.x*256+tid)
__global__ __launch_bounds__(256) void k_gru_enc(
    const float* __restrict__ gi,   // offset to step: [32,1536], bx included
    const float* __restrict__ Wh, const float* __restrict__ bh,
    const float* __restrict__ hin, float* __restrict__ hout,
    float* __restrict__ yout, int ystride)
{
    __shared__ float hs[512];
    int b = blockIdx.y;
    int i = blockIdx.x * 256 + threadIdx.x;
    hs[threadIdx.x]       = hin[b * 512 + threadIdx.x];
    hs[threadIdx.x + 256] = hin[b * 512 + threadIdx.x + 256];
    __syncthreads();

    const float4* w0 = (const float4*)(Wh + (size_t)i * 512);
    const float4* w1 = (const float4*)(Wh + (size_t)(i + 512) * 512);
    const float4* w2 = (const float4*)(Wh + (size_t)(i + 1024) * 512);
    float a0 = 0.f, a1 = 0.f, a2 = 0.f;
    #pragma unroll 4
    for (int kb = 0; kb < 128; kb++) {
        float4 p0 = w0[kb], p1 = w1[kb], p2 = w2[kb];
        const float* hp = &hs[kb * 4];
        FDOT4(a0, p0, hp); FDOT4(a1, p1, hp); FDOT4(a2, p2, hp);
    }
    const float* gir = gi + b * 1536;
    float gr  = gir[i]        + a0 + bh[i];
    float gz  = gir[i + 512]  + a1 + bh[i + 512];
    float gin = gir[i + 1024];
    float ghn = a2 + bh[i + 1024];
    float r = sigm(gr), z = sigm(gz);
    float n = tanhf(gin + r * ghn);
    float hnew = (1.f - z) * n + z * hs[i];
    hout[b * 512 + i] = hnew;
    yout[(size_t)b * ystride + i] = hnew;
}

// ---------------- decoder attention (per-b block) ----------------
__global__ __launch_bounds__(256) void k_attn(
    const float* __restrict__ h1,     // [32,512]
    const float* __restrict__ Wattn,  // [512,1024], cols 0..511 = hid part
    const float* __restrict__ preenc, // [32*64,512] row b*64+s (b_attn included)
    const float* __restrict__ enc,    // [32*64,512] row b*64+s
    const float* __restrict__ vattn,  // [512]
    float* __restrict__ ctx)          // [32,512]
{
    __shared__ float hs[512], ph[512], red[256], sc[64], aw[64];
    int b = blockIdx.x, tid = threadIdx.x;
    hs[tid]       = h1[b * 512 + tid];
    hs[tid + 256] = h1[b * 512 + tid + 256];
    __syncthreads();

    // ph = h1 @ Wattn[:, :512]^T
    #pragma unroll
    for (int jj = 0; jj < 2; jj++) {
        int j = tid + jj * 256;
        const float4* wp = (const float4*)(Wattn + (size_t)j * 1024);
        float a = 0.f;
        for (int kb = 0; kb < 128; kb++) {
            float4 p = wp[kb];
            const float* hp = &hs[kb * 4];
            FDOT4(a, p, hp);
        }
        ph[j] = a;
    }
    __syncthreads();

    // scores[s] = sum_h v[h]*tanh(preenc + ph)
    int s = tid >> 2, q = tid & 3;
    const float* pe = preenc + ((size_t)b * 64 + s) * 512;
    float part = 0.f;
    for (int h = q; h < 512; h += 4)
        part += vattn[h] * tanhf(pe[h] + ph[h]);
    red[tid] = part;
    __syncthreads();
    if (q == 0) sc[s] = red[tid] + red[tid + 1] + red[tid + 2] + red[tid + 3];
    __syncthreads();
    if (tid == 0) {
        float mx = -1e30f;
        for (int k = 0; k < 64; k++) mx = fmaxf(mx, sc[k]);
        float sum = 0.f;
        for (int k = 0; k < 64; k++) { float e = __expf(sc[k] - mx); aw[k] = e; sum += e; }
        float inv = 1.f / sum;
        for (int k = 0; k < 64; k++) aw[k] *= inv;
    }
    __syncthreads();

    // ctx = sum_s a[s] * enc_out[b,s,:]
    #pragma unroll
    for (int jj = 0; jj < 2; jj++) {
        int j = tid + jj * 256;
        float c = 0.f;
        for (int s2 = 0; s2 < 64; s2++)
            c += aw[s2] * enc[((size_t)b * 64 + s2) * 512 + j];
        ctx[b * 512 + j] = c;
    }
}

// ---------------- decoder GRU layer 0 step ----------------
__global__ __launch_bounds__(256) void k_gru_d0(
    const float* __restrict__ pregi,  // offset to step t: [32,1536] (emb part + bx)
    const float* __restrict__ Wh, const float* __restrict__ bh,
    const float* __restrict__ Wx,     // Wx_d0 [1536,768]; ctx cols = 256..767
    const float* __restrict__ ctx,
    const float* __restrict__ hin, float* __restrict__ hout)
{
    __shared__ float hs[512], cs[512];
    int b = blockIdx.y;
    int i = blockIdx.x * 256 + threadIdx.x;
    hs[threadIdx.x]       = hin[b * 512 + threadIdx.x];
    hs[threadIdx.x + 256] = hin[b * 512 + threadIdx.x + 256];
    cs[threadIdx.x]       = ctx[b * 512 + threadIdx.x];
    cs[threadIdx.x + 256] = ctx[b * 512 + threadIdx.x + 256];
    __syncthreads();

    const float4* wh0 = (const float4*)(Wh + (size_t)i * 512);
    const float4* wh1 = (const float4*)(Wh + (size_t)(i + 512) * 512);
    const float4* wh2 = (const float4*)(Wh + (size_t)(i + 1024) * 512);
    const float4* wc0 = (const float4*)(Wx + (size_t)i * 768 + 256);
    const float4* wc1 = (const float4*)(Wx + (size_t)(i + 512) * 768 + 256);
    const float4* wc2 = (const float4*)(Wx + (size_t)(i + 1024) * 768 + 256);
    float a0 = 0.f, a1 = 0.f, a2 = 0.f, c0 = 0.f, c1 = 0.f, c2 = 0.f;
    #pragma unroll 2
    for (int kb = 0; kb < 128; kb++) {
        const float* hp = &hs[kb * 4];
        const float* cp = &cs[kb * 4];
        float4 p0 = wh0[kb], p1 = wh1[kb], p2 = wh2[kb];
        float4 q0 = wc0[kb], q1 = wc1[kb], q2 = wc2[kb];
        FDOT4(a0, p0, hp); FDOT4(a1, p1, hp); FDOT4(a2, p2, hp);
        FDOT4(c0, q0, cp); FDOT4(c1, q1, cp); FDOT4(c2, q2, cp);
    }
    const float* gir = pregi + b * 1536;
    float gr  = gir[i]        + c0 + a0 + bh[i];
    float gz  = gir[i + 512]  + c1 + a1 + bh[i + 512];
    float gin = gir[i + 1024] + c2;
    float ghn = a2 + bh[i + 1024];
    float r = sigm(gr), z = sigm(gz);
    float n = tanhf(gin + r * ghn);
    hout[b * 512 + i] = (1.f - z) * n + z * hs[i];
}

// ---------------- decoder GRU layer 1 step ----------------
__global__ __launch_bounds__(256) void k_gru_d1(
    const float* __restrict__ Wx, const float* __restrict__ bx,
    const float* __restrict__ Wh, const float* __restrict__ bh,
    const float* __restrict__ x,     // new h0
    const float* __restrict__ hin, float* __restrict__ hout,
    float* __restrict__ H1step)      // offset to step t: [32,512]
{
    __shared__ float xs[512], hs[512];
    int b = blockIdx.y;
    int i = blockIdx.x * 256 + threadIdx.x;
    xs[threadIdx.x]       = x[b * 512 + threadIdx.x];
    xs[threadIdx.x + 256] = x[b * 512 + threadIdx.x + 256];
    hs[threadIdx.x]       = hin[b * 512 + threadIdx.x];
    hs[threadIdx.x + 256] = hin[b * 512 + threadIdx.x + 256];
    __syncthreads();

    const float4* wx0 = (const float4*)(Wx + (size_t)i * 512);
    const float4* wx1 = (const float4*)(Wx + (size_t)(i + 512) * 512);
    const float4* wx2 = (const float4*)(Wx + (size_t)(i + 1024) * 512);
    const float4* wh0 = (const float4*)(Wh + (size_t)i * 512);
    const float4* wh1 = (const float4*)(Wh + (size_t)(i + 512) * 512);
    const float4* wh2 = (const float4*)(Wh + (size_t)(i + 1024) * 512);
    float g0 = 0.f, g1 = 0.f, g2 = 0.f, a0 = 0.f, a1 = 0.f, a2 = 0.f;
    #pragma unroll 2
    for (int kb = 0; kb < 128; kb++) {
        const float* xp = &xs[kb * 4];
        const float* hp = &hs[kb * 4];
        float4 p0 = wx0[kb], p1 = wx1[kb], p2 = wx2[kb];
        float4 q0 = wh0[kb], q1 = wh1[kb], q2 = wh2[kb];
        FDOT4(g0, p0, xp); FDOT4(g1, p1, xp); FDOT4(g2, p2, xp);
        FDOT4(a0, q0, hp); FDOT4(a1, q1, hp); FDOT4(a2, q2, hp);
    }
    float gr  = g0 + bx[i]        + a0 + bh[i];
    float gz  = g1 + bx[i + 512]  + a1 + bh[i + 512];
    float gin = g2 + bx[i + 1024];
    float ghn = a2 + bh[i + 1024];
    float r = sigm(gr), z = sigm(gz);
    float n = tanhf(gin + r * ghn);
    float hnew = (1.f - z) * n + z * hs[i];
    hout[b * 512 + i] = hnew;
    H1step[(size_t)b * 512 + i] = hnew;
}

// ---------------- host ----------------
extern "C" void kernel_launch(void* const* d_in, const int* in_sizes, int n_in,
                              void* d_out, int out_size, void* d_ws, size_t ws_size,
                              hipStream_t stream)
{
    const int*   seq    = (const int*)d_in[0];
    const int*   tgt    = (const int*)d_in[1];
    const float* E_enc  = (const float*)d_in[2];
    const float* Wx_e0  = (const float*)d_in[3];
    const float* Wh_e0  = (const float*)d_in[4];
    const float* bx_e0  = (const float*)d_in[5];
    const float* bh_e0  = (const float*)d_in[6];
    const float* Wx_e1  = (const float*)d_in[7];
    const float* Wh_e1  = (const float*)d_in[8];
    const float* bx_e1  = (const float*)d_in[9];
    const float* bh_e1  = (const float*)d_in[10];
    const float* E_dec  = (const float*)d_in[11];
    const float* W_attn = (const float*)d_in[12];
    const float* b_attn = (const float*)d_in[13];
    const float* v_attn = (const float*)d_in[14];
    const float* Wx_d0  = (const float*)d_in[15];
    const float* Wh_d0  = (const float*)d_in[16];
    const float* bx_d0  = (const float*)d_in[17];
    const float* bh_d0  = (const float*)d_in[18];
    const float* Wx_d1  = (const float*)d_in[19];
    const float* Wh_d1  = (const float*)d_in[20];
    const float* bx_d1  = (const float*)d_in[21];
    const float* bh_d1  = (const float*)d_in[22];
    const float* W_out  = (const float*)d_in[23];
    const float* b_out  = (const float*)d_in[24];
    float* out = (float*)d_out;

    char* ws = (char*)d_ws;
    size_t off = 0;
    auto alloc = [&](size_t bytes) -> void* {
        void* p = ws + off; off += (bytes + 255) & ~(size_t)255; return p;
    };
    float* emb_e   = (float*)alloc((size_t)2048 * 256 * 4);
    float* gi_buf  = (float*)alloc((size_t)2048 * 1536 * 4);
    float* y0      = (float*)alloc((size_t)2048 * 512 * 4);
    float* enc_out = (float*)alloc((size_t)2048 * 512 * 4);
    float* pre_enc = (float*)alloc((size_t)2048 * 512 * 4);
    float* emb_d   = (float*)alloc((size_t)2048 * 256 * 4);
    float* pre_gid = (float*)alloc((size_t)2048 * 1536 * 4);
    float* H1      = (float*)alloc((size_t)2048 * 512 * 4);
    float* hA0 = (float*)alloc(32 * 512 * 4);
    float* hB0 = (float*)alloc(32 * 512 * 4);
    float* hA1 = (float*)alloc(32 * 512 * 4);
    float* hB1 = (float*)alloc(32 * 512 * 4);
    float* ctx = (float*)alloc(32 * 512 * 4);

    // zero initial hidden states (ws is poisoned before every call)
    k_zero2<<<dim3(64), dim3(256), 0, stream>>>(hA0, hA1);

    // ---- encoder ----
    k_gather_enc<<<dim3(2048), dim3(64), 0, stream>>>(seq, E_enc, emb_e);
    // gi0 = emb @ Wx_e0^T + bx_e0   (rows s*32+b)
    k_sgemm<<<dim3(24, 32), dim3(256), 0, stream>>>(
        emb_e, 256, Wx_e0, 256, 0, bx_e0, gi_buf, 1536, 256, 0);
    {
        float *cur = hA0, *nxt = hB0;
        for (int s = 0; s < 64; s++) {
            k_gru_enc<<<dim3(2, 32), dim3(256), 0, stream>>>(
                gi_buf + (size_t)s * 32 * 1536, Wh_e0, bh_e0, cur, nxt,
                y0 + (size_t)s * 32 * 512, 512);
            float* t = cur; cur = nxt; nxt = t;
        }
        // he0 ends in hA0 (64 swaps, even)
    }
    // gi1 = y0 @ Wx_e1^T + bx_e1
    k_sgemm<<<dim3(24, 32), dim3(256), 0, stream>>>(
        y0, 512, Wx_e1, 512, 0, bx_e1, gi_buf, 1536, 512, 0);
    {
        float *cur = hA1, *nxt = hB1;
        for (int s = 0; s < 64; s++) {
            // enc_out row = b*64+s -> base + s*512, stride_b = 64*512
            k_gru_enc<<<dim3(2, 32), dim3(256), 0, stream>>>(
                gi_buf + (size_t)s * 32 * 1536, Wh_e1, bh_e1, cur, nxt,
                enc_out + (size_t)s * 512, 64 * 512);
            float* t = cur; cur = nxt; nxt = t;
        }
        // he1 in hA1
    }

    // ---- decoder precompute ----
    // pre_enc = enc_out @ W_attn[:,512:]^T + b_attn   (rows b*64+s)
    k_sgemm<<<dim3(8, 32), dim3(256), 0, stream>>>(
        enc_out, 512, W_attn, 1024, 512, b_attn, pre_enc, 512, 512, 0);
    k_gather_dec<<<dim3(2048), dim3(64), 0, stream>>>(tgt, E_dec, emb_d);
    // pre_gid = emb_d @ Wx_d0[:, :256]^T + bx_d0   (rows t*32+b)
    k_sgemm<<<dim3(24, 32), dim3(256), 0, stream>>>(
        emb_d, 256, Wx_d0, 768, 0, bx_d0, pre_gid, 1536, 256, 0);

    // ---- decoder loop ----
    {
        float *c0 = hA0, *n0 = hB0, *c1 = hA1, *n1 = hB1;
        for (int t = 0; t < 64; t++) {
            k_attn<<<dim3(32), dim3(256), 0, stream>>>(
                c1, W_attn, pre_enc, enc_out, v_attn, ctx);
            k_gru_d0<<<dim3(2, 32), dim3(256), 0, stream>>>(
                pre_gid + (size_t)t * 32 * 1536, Wh_d0, bh_d0, Wx_d0, ctx, c0, n0);
            k_gru_d1<<<dim3(2, 32), dim3(256), 0, stream>>>(
                Wx_d1, bx_d1, Wh_d1, bh_d1, n0, c1, n1, H1 + (size_t)t * 32 * 512);
            float* tmp;
            tmp = c0; c0 = n0; n0 = tmp;
            tmp = c1; c1 = n1; n1 = tmp;
        }
    }

    // ---- logits = H1 @ W_out^T + b_out, written as out[b,t,v] (fp32) ----
    k_sgemm<<<dim3(500, 32), dim3(256), 0, stream>>>(
        H1, 512, W_out, 512, 0, b_out, out, 32000, 512, 1);

    (void)in_sizes; (void)n_in; (void)out_size; (void)ws_size;
}